// Round 3
// baseline (350.421 us; speedup 1.0000x reference)
//
#include <hip/hip_runtime.h>
#include <cstdint>
#include <cstddef>

typedef unsigned short ushort_t;
typedef unsigned int uint;

typedef __attribute__((ext_vector_type(8))) short short8;   // 8 x bf16 (4 VGPRs)
typedef __attribute__((ext_vector_type(4))) float floatx4;  // 4 x f32

#define CDIM 768

// ---------- bf16 helpers (raw ushort representation) ----------
__device__ __forceinline__ float bfu(ushort_t u) {
    return __uint_as_float(((uint)u) << 16);
}
__device__ __forceinline__ void bf2(uint u, float& lo, float& hi) {
    lo = __uint_as_float(u << 16);
    hi = __uint_as_float(u & 0xffff0000u);
}
__device__ __forceinline__ ushort_t f2bfu(float f) {
    uint u = __float_as_uint(f);
    u += 0x7fffu + ((u >> 16) & 1u);   // round-to-nearest-even
    return (ushort_t)(u >> 16);
}
__device__ __forceinline__ uint pack2(float a, float b) {     // RNE pack
    return (uint)f2bfu(a) | ((uint)f2bfu(b) << 16);
}
// packed RNE f32x2 -> bf16x2 (low word = first operand), 1 VALU inst
__device__ __forceinline__ uint cvt2(float lo, float hi) {
    uint r;
    asm("v_cvt_pk_bf16_f32 %0, %1, %2" : "=v"(r) : "v"(lo), "v"(hi));
    return r;
}
__device__ __forceinline__ void gload_lds16(const void* g, void* l) {
    __builtin_amdgcn_global_load_lds(
        (__attribute__((address_space(1))) void*)(uintptr_t)g,
        (__attribute__((address_space(3))) void*)l, 16, 0, 0);
}

// ---------- Kernel 0a: convert Wq/Wk/Wv (fp32) -> bf16, RNE ----------
__global__ __launch_bounds__(256) void cvt_w(
    const float* __restrict__ Wq, const float* __restrict__ Wk,
    const float* __restrict__ Wv, ushort_t* __restrict__ wb)
{
    const int m = blockIdx.y;
    const float* src = (m == 0) ? Wq : (m == 1 ? Wk : Wv);
    ushort_t* dst = wb + (size_t)m * 589824;
    const int i = (blockIdx.x * 256 + threadIdx.x) * 8;
    const float4 f0 = *(const float4*)(src + i);
    const float4 f1 = *(const float4*)(src + i + 4);
    uint4 u;
    u.x = pack2(f0.x, f0.y);
    u.y = pack2(f0.z, f0.w);
    u.z = pack2(f1.x, f1.y);
    u.w = pack2(f1.z, f1.w);
    *(uint4*)(dst + i) = u;
}

// ---------- Kernel 0b: init agent accumulator with the q-bias ----------
__global__ __launch_bounds__(256) void init_agent(const float* __restrict__ bq,
                                                  float* __restrict__ agent)
{
    const int bh = blockIdx.x;          // 96
    const int h = bh % 12;
    for (int i = threadIdx.x; i < 1024; i += 256)
        agent[(size_t)bh * 1024 + i] = bq[h * 64 + (i & 63)];
}

// ---------- Kernel 1: fused QKV GEMM ----------
// Round-2 structure + counted-vmcnt staging barrier:
//  - A (fp32) register-prefetched 1.5 tiles ahead (ra0/ra1 rotate), converted
//    in-register (v_cvt_pk_bf16_f32) and ds_written into the XOR-swizzled layout.
//  - barrier #2 is a raw s_barrier with s_waitcnt vmcnt(8): waits the 4 W
//    gload_lds (issued first) while the 8 next-tile A loads stay in flight.
//  - instruction order pinned with sched_barrier(0): [W gloads][A loads][cvt]
//    so the vmcnt count is exact. Last tile (no prefetch) uses vmcnt(0).
__global__ __launch_bounds__(256, 2) void gemm_qkv(
    const float* __restrict__ s1, const float* __restrict__ s2,
    const ushort_t* __restrict__ wb,
    const float* __restrict__ bq, const float* __restrict__ bk, const float* __restrict__ bv,
    ushort_t* __restrict__ qo, ushort_t* __restrict__ ko, ushort_t* __restrict__ vo,
    float* __restrict__ agent)
{
    const int z = blockIdx.z;
    const float* A        = (z == 0) ? s1 : s2;
    const ushort_t* W     = wb + (size_t)z * 589824;
    const float* bias     = (z == 0) ? bq : (z == 1 ? bk : bv);
    ushort_t* out         = (z == 0) ? qo : (z == 1 ? ko : vo);

    __shared__ ushort_t At[128 * 64];   // 16 KB
    __shared__ ushort_t Wt[128 * 64];   // 16 KB

    const int tid  = threadIdx.x;
    const int wave = tid >> 6;
    const int lane = tid & 63;
    const int wm = wave >> 1, wn = wave & 1;

    // XCD-aware swizzle: 1536 blocks/plane, 8 XCDs, 192 blocks/chunk (bijective).
    const int id   = blockIdx.x + (blockIdx.y << 8);   // gridDim.x = 256
    const int id2  = (id & 7) * 192 + (id >> 3);
    const int row0 = (id2 / 6) * 128;   // token rows (b*4096+m)
    const int col0 = (id2 % 6) * 128;   // output channels

    // staging geometry: lane j covers row_off = j>>3, source chunk = (j&7) ^ (j>>3)
    const int sro = lane >> 3;
    const int sch = ((lane & 7) ^ sro) * 8;
    const float*    gaF = A + (size_t)(row0 + wave * 32 + sro) * CDIM + sch;
    const ushort_t* gwB = W + (size_t)(col0 + wave * 32 + sro) * CDIM + sch;

    floatx4 acc[4][4];
    #pragma unroll
    for (int i = 0; i < 4; ++i)
        #pragma unroll
        for (int j = 0; j < 4; ++j)
            acc[i][j] = (floatx4){0.f, 0.f, 0.f, 0.f};

    const int q4 = lane >> 4, r16 = lane & 15;

    float4 ra0[4][2], ra1[4][2];
    #pragma unroll
    for (int i = 0; i < 4; ++i) {
        const float* p = gaF + (size_t)i * 8 * CDIM;      // kt = 0
        ra0[i][0] = *(const float4*)(p);
        ra0[i][1] = *(const float4*)(p + 4);
    }

    // one staging+compute step; ra_cur holds tile kt, prefetches tile kt+64 into ra_nxt
    #define GEMM_STEP(kt, ra_cur, ra_nxt, LAST)                                        \
    {                                                                                  \
        __syncthreads();                                                               \
        _Pragma("unroll")                                                              \
        for (int i = 0; i < 4; ++i)                                                    \
            gload_lds16(gwB + (size_t)i * 8 * CDIM + (kt), &Wt[(wave*32 + i*8) * 64]); \
        __builtin_amdgcn_sched_barrier(0);                                             \
        if (!(LAST)) {                                                                 \
            _Pragma("unroll")                                                          \
            for (int i = 0; i < 4; ++i) {                                              \
                const float* p = gaF + (size_t)i * 8 * CDIM + (kt) + 64;               \
                ra_nxt[i][0] = *(const float4*)(p);                                    \
                ra_nxt[i][1] = *(const float4*)(p + 4);                                \
            }                                                                          \
        }                                                                              \
        __builtin_amdgcn_sched_barrier(0);                                             \
        _Pragma("unroll")                                                              \
        for (int i = 0; i < 4; ++i) {                                                  \
            uint4 u;                                                                   \
            u.x = cvt2(ra_cur[i][0].x, ra_cur[i][0].y);                                \
            u.y = cvt2(ra_cur[i][0].z, ra_cur[i][0].w);                                \
            u.z = cvt2(ra_cur[i][1].x, ra_cur[i][1].y);                                \
            u.w = cvt2(ra_cur[i][1].z, ra_cur[i][1].w);                                \
            *(uint4*)&At[(wave * 32 + i * 8 + sro) * 64 + (lane & 7) * 8] = u;         \
        }                                                                              \
        if (!(LAST)) { asm volatile("s_waitcnt vmcnt(8) lgkmcnt(0)" ::: "memory"); }   \
        else         { asm volatile("s_waitcnt vmcnt(0) lgkmcnt(0)" ::: "memory"); }   \
        __builtin_amdgcn_sched_barrier(0);                                             \
        __builtin_amdgcn_s_barrier();                                                  \
        _Pragma("unroll")                                                              \
        for (int ks = 0; ks < 2; ++ks) {                                               \
            short8 af[4], bfr[4];                                                      \
            _Pragma("unroll")                                                          \
            for (int mt = 0; mt < 4; ++mt) {                                           \
                const int row = wm * 64 + mt * 16 + r16;                               \
                const int ch  = (ks * 4 + q4) ^ (row & 7);                             \
                af[mt] = *(const short8*)&At[row * 64 + ch * 8];                       \
            }                                                                          \
            _Pragma("unroll")                                                          \
            for (int nt = 0; nt < 4; ++nt) {                                           \
                const int row = wn * 64 + nt * 16 + r16;                               \
                const int ch  = (ks * 4 + q4) ^ (row & 7);                             \
                bfr[nt] = *(const short8*)&Wt[row * 64 + ch * 8];                      \
            }                                                                          \
            _Pragma("unroll")                                                          \
            for (int mt = 0; mt < 4; ++mt)                                             \
                _Pragma("unroll")                                                      \
                for (int nt = 0; nt < 4; ++nt)                                         \
                    acc[mt][nt] = __builtin_amdgcn_mfma_f32_16x16x32_bf16(             \
                        af[mt], bfr[nt], acc[mt][nt], 0, 0, 0);                        \
        }                                                                              \
    }

    for (int kt = 0; kt < CDIM; kt += 128) {
        GEMM_STEP(kt,      ra0, ra1, false);
        GEMM_STEP(kt + 64, ra1, ra0, (kt + 128 >= CDIM));
    }
    #undef GEMM_STEP

    // epilogue: C/D layout col=lane&15, row=(lane>>4)*4+reg -> head-major store.
    // z==0 additionally folds the adaptive-avg-pool (block's 128 rows lie in one
    // agent chunk): shfl-reduce over q4 lanes, one atomicAdd per col per wave.
    const int b = row0 >> 12;
    const int m_base = row0 & 4095;
    #pragma unroll
    for (int nt = 0; nt < 4; ++nt) {
        const int col = col0 + wn * 64 + nt * 16 + r16;
        const int h = col >> 6, d = col & 63;
        const float bb = bias[col];
        ushort_t* ob = out + ((size_t)(b * 12 + h) * 4096) * 64 + d;
        float psum = 0.f;
        #pragma unroll
        for (int mt = 0; mt < 4; ++mt) {
            const int m = m_base + wm * 64 + mt * 16 + q4 * 4;
            #pragma unroll
            for (int r = 0; r < 4; ++r) {
                ob[(size_t)(m + r) * 64] = f2bfu(acc[mt][nt][r] + bb);
                psum += acc[mt][nt][r];
            }
        }
        if (z == 0) {
            psum += __shfl_xor(psum, 16);
            psum += __shfl_xor(psum, 32);
            if (q4 == 0)
                atomicAdd(&agent[(size_t)(b * 12 + h) * 1024 + (m_base >> 8) * 64 + d],
                          psum * (1.0f / 256.0f));
        }
    }
}

// ---------- Kernel 3: stage-2 agent bias ab[h][a] (fp32) ----------
__global__ void bias_ab_k(const float* __restrict__ na, const float* __restrict__ ha,
                          const float* __restrict__ wa, float* __restrict__ ab)
{
    const int t = threadIdx.x;
    if (t >= 192) return;
    const int h = t >> 4, a = t & 15;
    const float cw[7] = {2.25f, 2.34375f, 2.28125f, 2.25f, 2.28125f, 2.34375f, 2.25f};
    float acc = 0.f;
    const float* nb = na + (h * 16 + a) * 49;
    for (int i = 0; i < 7; ++i)
        for (int j = 0; j < 7; ++j)
            acc += cw[i] * cw[j] * nb[i * 7 + j];
    acc *= (1.0f / 256.0f);
    float s = 0.f;
    for (int p = 0; p < 16; ++p)
        s += ha[(h * 16 + p) * 16 + a] + wa[(h * 16 + p) * 16 + a];
    ab[t] = acc + s * (1.0f / 16.0f);
}

// ---------- Kernel 4: stage 1 (agent -> keys/values), head-major, z-split x8 ----------
__global__ __launch_bounds__(256) void stage1(
    const ushort_t* __restrict__ k_hm, const ushort_t* __restrict__ v_hm,
    const float* __restrict__ agent, float* __restrict__ Sp, float* __restrict__ avp)
{
    const int bh = blockIdx.x, z = blockIdx.y;
    const int tid = threadIdx.x;
    __shared__ float ahs[1024];          // ah * scale, [a][d]
    __shared__ ushort_t E2[512 * 20];    // [m_local][a] bf16, row padded to 40 B

    for (int i = tid; i < 1024; i += 256)
        ahs[i] = agent[(size_t)bh * 1024 + i] * 0.125f;
    __syncthreads();

    const int m0 = z * 512;
    const ushort_t* kb = k_hm + ((size_t)bh * 4096 + m0) * 64;

    {
        const uint4* krA = (const uint4*)(kb + (size_t)tid * 64);
        const uint4* krB = (const uint4*)(kb + (size_t)(tid + 256) * 64);
        uint kuA[16], kuB[16];
        #pragma unroll
        for (int i = 0; i < 4; ++i) {
            uint4 ua = krA[i], ub = krB[i];
            kuA[i*4+0] = ua.x; kuA[i*4+1] = ua.y; kuA[i*4+2] = ua.z; kuA[i*4+3] = ua.w;
            kuB[i*4+0] = ub.x; kuB[i*4+1] = ub.y; kuB[i*4+2] = ub.z; kuB[i*4+3] = ub.w;
        }
        float dsA[16], dsB[16];
        #pragma unroll
        for (int a = 0; a < 16; ++a) { dsA[a] = 0.f; dsB[a] = 0.f; }
        #pragma unroll
        for (int c = 0; c < 16; ++c) {
            float a0, a1, a2, a3, b0, b1, b2, b3;
            bf2(kuA[2*c],   a0, a1); bf2(kuA[2*c+1], a2, a3);
            bf2(kuB[2*c],   b0, b1); bf2(kuB[2*c+1], b2, b3);
            #pragma unroll
            for (int a = 0; a < 16; ++a) {
                const floatx4 av = *(const floatx4*)&ahs[a * 64 + c * 4];
                dsA[a] += a0 * av[0] + a1 * av[1] + a2 * av[2] + a3 * av[3];
                dsB[a] += b0 * av[0] + b1 * av[1] + b2 * av[2] + b3 * av[3];
            }
        }
        uint eA[8], eB[8];
        #pragma unroll
        for (int a2 = 0; a2 < 8; ++a2) {
            eA[a2] = pack2(__expf(dsA[2*a2]), __expf(dsA[2*a2+1]));
            eB[a2] = pack2(__expf(dsB[2*a2]), __expf(dsB[2*a2+1]));
        }
        uint2* dA = (uint2*)&E2[(size_t)tid * 20];
        uint2* dB = (uint2*)&E2[(size_t)(tid + 256) * 20];
        dA[0] = make_uint2(eA[0], eA[1]); dA[1] = make_uint2(eA[2], eA[3]);
        dA[2] = make_uint2(eA[4], eA[5]); dA[3] = make_uint2(eA[6], eA[7]);
        dB[0] = make_uint2(eB[0], eB[1]); dB[1] = make_uint2(eB[2], eB[3]);
        dB[2] = make_uint2(eB[4], eB[5]); dB[3] = make_uint2(eB[6], eB[7]);
    }
    __syncthreads();

    const int d = tid & 63, g = tid >> 6;
    const ushort_t* vb = v_hm + ((size_t)bh * 4096 + m0) * 64 + d;
    float acc0 = 0, acc1 = 0, acc2 = 0, acc3 = 0;
    float ss0 = 0, ss1 = 0, ss2 = 0, ss3 = 0;
    for (int ml = 0; ml < 512; ++ml) {
        const float vv = bfu(vb[(size_t)ml * 64]);
        const uint2 ee = *(const uint2*)&E2[(size_t)ml * 20 + g * 4];
        float e0, e1, e2, e3;
        bf2(ee.x, e0, e1);
        bf2(ee.y, e2, e3);
        acc0 += e0 * vv; ss0 += e0;
        acc1 += e1 * vv; ss1 += e1;
        acc2 += e2 * vv; ss2 += e2;
        acc3 += e3 * vv; ss3 += e3;
    }
    float* avz = avp + (size_t)(z * 96 + bh) * 1024;
    avz[(g * 4 + 0) * 64 + d] = acc0;
    avz[(g * 4 + 1) * 64 + d] = acc1;
    avz[(g * 4 + 2) * 64 + d] = acc2;
    avz[(g * 4 + 3) * 64 + d] = acc3;
    if (d == 0) {
        float* Sz = Sp + (z * 96 + bh) * 16;
        Sz[g * 4 + 0] = ss0;
        Sz[g * 4 + 1] = ss1;
        Sz[g * 4 + 2] = ss2;
        Sz[g * 4 + 3] = ss3;
    }
}

// ---------- Kernel 5: stage 2 (queries -> agents) + fp32 output ----------
__global__ __launch_bounds__(256) void stage2(
    const ushort_t* __restrict__ q_hm, const float* __restrict__ avp,
    const float* __restrict__ Sp, const float* __restrict__ agent,
    const float* __restrict__ ab, float* __restrict__ out)
{
    const int nb = blockIdx.x, bh = blockIdx.y;
    const int b = bh / 12, h = bh % 12;
    const int tid = threadIdx.x;
    __shared__ float ahs[1024];
    __shared__ float avn[1024];
    __shared__ float abl[16];

    for (int i = tid; i < 1024; i += 256) {
        const int a = i >> 6;
        ahs[i] = agent[(size_t)bh * 1024 + i] * 0.125f;
        float num = 0.f, den = 0.f;
        #pragma unroll
        for (int zz = 0; zz < 8; ++zz) {
            num += avp[(size_t)(zz * 96 + bh) * 1024 + i];
            den += Sp[(zz * 96 + bh) * 16 + a];
        }
        avn[i] = num / den;
    }
    if (tid < 16) abl[tid] = ab[h * 16 + tid];
    __syncthreads();

    const int n0 = nb * 512;
    const uint4* qrA = (const uint4*)(q_hm + ((size_t)bh * 4096 + n0 + tid) * 64);
    const uint4* qrB = (const uint4*)(q_hm + ((size_t)bh * 4096 + n0 + tid + 256) * 64);
    uint quA[16], quB[16];
    #pragma unroll
    for (int i = 0; i < 4; ++i) {
        uint4 ua = qrA[i], ub = qrB[i];
        quA[i*4+0] = ua.x; quA[i*4+1] = ua.y; quA[i*4+2] = ua.z; quA[i*4+3] = ua.w;
        quB[i*4+0] = ub.x; quB[i*4+1] = ub.y; quB[i*4+2] = ub.z; quB[i*4+3] = ub.w;
    }
    float dsA[16], dsB[16];
    #pragma unroll
    for (int a = 0; a < 16; ++a) { float t = abl[a]; dsA[a] = t; dsB[a] = t; }
    #pragma unroll
    for (int c = 0; c < 16; ++c) {
        float a0, a1, a2, a3, b0, b1, b2, b3;
        bf2(quA[2*c],   a0, a1); bf2(quA[2*c+1], a2, a3);
        bf2(quB[2*c],   b0, b1); bf2(quB[2*c+1], b2, b3);
        #pragma unroll
        for (int a = 0; a < 16; ++a) {
            const floatx4 av = *(const floatx4*)&ahs[a * 64 + c * 4];
            dsA[a] += a0 * av[0] + a1 * av[1] + a2 * av[2] + a3 * av[3];
            dsB[a] += b0 * av[0] + b1 * av[1] + b2 * av[2] + b3 * av[3];
        }
    }
    float psA = 0.f, psB = 0.f;
    #pragma unroll
    for (int a = 0; a < 16; ++a) {
        dsA[a] = __expf(dsA[a]); psA += dsA[a];
        dsB[a] = __expf(dsB[a]); psB += dsB[a];
    }
    const float rA = 1.0f / psA, rB = 1.0f / psB;
    #pragma unroll
    for (int a = 0; a < 16; ++a) { dsA[a] *= rA; dsB[a] *= rB; }

    float* oA = out + ((size_t)b * 4096 + n0 + tid) * CDIM + h * 64;
    float* oB = oA + (size_t)256 * CDIM;
    #pragma unroll
    for (int dc = 0; dc < 16; ++dc) {
        floatx4 sA = {0.f, 0.f, 0.f, 0.f}, sB = {0.f, 0.f, 0.f, 0.f};
        #pragma unroll
        for (int a = 0; a < 16; ++a) {
            const floatx4 av = *(const floatx4*)&avn[a * 64 + dc * 4];
            sA += dsA[a] * av;
            sB += dsB[a] * av;
        }
        *(floatx4*)(oA + dc * 4) = sA;
        *(floatx4*)(oB + dc * 4) = sB;
    }
}

// ---------- launcher ----------
extern "C" void kernel_launch(void* const* d_in, const int* in_sizes, int n_in,
                              void* d_out, int out_size, void* d_ws, size_t ws_size,
                              hipStream_t stream) {
    (void)in_sizes; (void)n_in; (void)out_size; (void)ws_size;
    const float* s1 = (const float*)d_in[0];
    const float* s2 = (const float*)d_in[1];
    const float* Wq = (const float*)d_in[2];
    const float* bq = (const float*)d_in[3];
    const float* Wk = (const float*)d_in[4];
    const float* bk = (const float*)d_in[5];
    const float* Wv = (const float*)d_in[6];
    const float* bv = (const float*)d_in[7];
    const float* na = (const float*)d_in[9];
    const float* ha = (const float*)d_in[12];
    const float* wa = (const float*)d_in[13];
    float* out = (float*)d_out;

    char* ws = (char*)d_ws;
    ushort_t* q_hm = (ushort_t*)(ws);                 // 50,331,648 B  [96][4096][64]
    ushort_t* k_hm = (ushort_t*)(ws + 50331648);      // 50,331,648 B
    ushort_t* v_hm = (ushort_t*)(ws + 100663296);     // 50,331,648 B
    float* agent   = (float*)(ws + 150994944);        //    393,216 B  [96][16][64]
    float* Sp      = (float*)(ws + 151388160);        //     49,152 B  [8][96][16]
    float* avp     = (float*)(ws + 151437312);        //  3,145,728 B  [8][96][16][64]
    float* ab      = (float*)(ws + 154583040);        //        768 B
    ushort_t* wb   = (ushort_t*)(ws + 154583808);     //  3,538,944 B  [3][768][768]

    cvt_w      <<<dim3(288, 3),    256, 0, stream>>>(Wq, Wk, Wv, wb);
    init_agent <<<dim3(96),        256, 0, stream>>>(bq, agent);
    gemm_qkv   <<<dim3(256, 6, 3), 256, 0, stream>>>(s1, s2, wb, bq, bk, bv,
                                                     q_hm, k_hm, v_hm, agent);
    bias_ab_k  <<<1, 256, 0, stream>>>(na, ha, wa, ab);
    stage1     <<<dim3(96, 8),     256, 0, stream>>>(k_hm, v_hm, agent, Sp, avp);
    stage2     <<<dim3(8, 96),     256, 0, stream>>>(q_hm, avp, Sp, agent, ab, out);
}

// Round 4
// 330.288 us; speedup vs baseline: 1.0610x; 1.0610x over previous
//
#include <hip/hip_runtime.h>
#include <cstdint>
#include <cstddef>

typedef unsigned short ushort_t;
typedef unsigned int uint;

typedef __attribute__((ext_vector_type(8))) short short8;   // 8 x bf16 (4 VGPRs)
typedef __attribute__((ext_vector_type(4))) float floatx4;  // 4 x f32

#define CDIM 768

// ---------- bf16 helpers (raw ushort representation) ----------
__device__ __forceinline__ float bfu(ushort_t u) {
    return __uint_as_float(((uint)u) << 16);
}
__device__ __forceinline__ void bf2(uint u, float& lo, float& hi) {
    lo = __uint_as_float(u << 16);
    hi = __uint_as_float(u & 0xffff0000u);
}
__device__ __forceinline__ ushort_t f2bfu(float f) {
    uint u = __float_as_uint(f);
    u += 0x7fffu + ((u >> 16) & 1u);   // round-to-nearest-even
    return (ushort_t)(u >> 16);
}
__device__ __forceinline__ uint pack2(float a, float b) {     // RNE pack
    return (uint)f2bfu(a) | ((uint)f2bfu(b) << 16);
}
// packed RNE f32x2 -> bf16x2 (low word = first operand), 1 VALU inst
__device__ __forceinline__ uint cvt2(float lo, float hi) {
    uint r;
    asm("v_cvt_pk_bf16_f32 %0, %1, %2" : "=v"(r) : "v"(lo), "v"(hi));
    return r;
}
__device__ __forceinline__ void gload_lds16(const void* g, void* l) {
    __builtin_amdgcn_global_load_lds(
        (__attribute__((address_space(1))) void*)(uintptr_t)g,
        (__attribute__((address_space(3))) void*)l, 16, 0, 0);
}

// ---------- Kernel 0a: convert Wq/Wk/Wv (fp32) -> bf16, RNE ----------
__global__ __launch_bounds__(256) void cvt_w(
    const float* __restrict__ Wq, const float* __restrict__ Wk,
    const float* __restrict__ Wv, ushort_t* __restrict__ wb)
{
    const int m = blockIdx.y;
    const float* src = (m == 0) ? Wq : (m == 1 ? Wk : Wv);
    ushort_t* dst = wb + (size_t)m * 589824;
    const int i = (blockIdx.x * 256 + threadIdx.x) * 8;
    const float4 f0 = *(const float4*)(src + i);
    const float4 f1 = *(const float4*)(src + i + 4);
    uint4 u;
    u.x = pack2(f0.x, f0.y);
    u.y = pack2(f0.z, f0.w);
    u.z = pack2(f1.x, f1.y);
    u.w = pack2(f1.z, f1.w);
    *(uint4*)(dst + i) = u;
}

// ---------- Kernel 0b: init agent accumulator with the q-bias ----------
__global__ __launch_bounds__(256) void init_agent(const float* __restrict__ bq,
                                                  float* __restrict__ agent)
{
    const int bh = blockIdx.x;          // 96
    const int h = bh % 12;
    for (int i = threadIdx.x; i < 1024; i += 256)
        agent[(size_t)bh * 1024 + i] = bq[h * 64 + (i & 63)];
}

// ---------- Kernel 1: fused QKV GEMM ----------
// Round-0 barrier profile + fused fp32->bf16 A-path:
//  staging window (between barriers): ONLY load issues — W via gload_lds,
//    next tile's A fp32 into registers. Both drain together at barrier (b).
//  compute region: cvt(ra) -> ds_write into At[buf^1] (double-buffered),
//    overlapped with MFMA on At[buf] (separate pipes); ds_writes are
//    lgkm-drained by the next top __syncthreads.
//  No sched_barrier / inline waitcnt — compiler schedules freely.
__global__ __launch_bounds__(256, 3) void gemm_qkv(
    const float* __restrict__ s1, const float* __restrict__ s2,
    const ushort_t* __restrict__ wb,
    const float* __restrict__ bq, const float* __restrict__ bk, const float* __restrict__ bv,
    ushort_t* __restrict__ qo, ushort_t* __restrict__ ko, ushort_t* __restrict__ vo,
    float* __restrict__ agent)
{
    const int z = blockIdx.z;
    const float* A        = (z == 0) ? s1 : s2;
    const ushort_t* W     = wb + (size_t)z * 589824;
    const float* bias     = (z == 0) ? bq : (z == 1 ? bk : bv);
    ushort_t* out         = (z == 0) ? qo : (z == 1 ? ko : vo);

    __shared__ ushort_t At[2][128 * 64];   // 32 KB (double-buffered)
    __shared__ ushort_t Wt[128 * 64];      // 16 KB

    const int tid  = threadIdx.x;
    const int wave = tid >> 6;
    const int lane = tid & 63;
    const int wm = wave >> 1, wn = wave & 1;

    // XCD-aware swizzle: 1536 blocks/plane, 8 XCDs, 192 blocks/chunk (bijective).
    const int id   = blockIdx.x + (blockIdx.y << 8);   // gridDim.x = 256
    const int id2  = (id & 7) * 192 + (id >> 3);
    const int row0 = (id2 / 6) * 128;   // token rows (b*4096+m)
    const int col0 = (id2 % 6) * 128;   // output channels

    // staging geometry: lane j covers row_off = j>>3, source chunk = (j&7) ^ (j>>3)
    const int sro = lane >> 3;
    const int sch = ((lane & 7) ^ sro) * 8;
    const float*    gaF = A + (size_t)(row0 + wave * 32 + sro) * CDIM + sch;
    const ushort_t* gwB = W + (size_t)(col0 + wave * 32 + sro) * CDIM + sch;

    floatx4 acc[4][4];
    #pragma unroll
    for (int i = 0; i < 4; ++i)
        #pragma unroll
        for (int j = 0; j < 4; ++j)
            acc[i][j] = (floatx4){0.f, 0.f, 0.f, 0.f};

    const int q4 = lane >> 4, r16 = lane & 15;

    // prologue: load + convert tile 0 into At[0] (serialized once)
    float4 ra[4][2];
    #pragma unroll
    for (int i = 0; i < 4; ++i) {
        const float* p = gaF + (size_t)i * 8 * CDIM;
        ra[i][0] = *(const float4*)(p);
        ra[i][1] = *(const float4*)(p + 4);
    }
    #pragma unroll
    for (int i = 0; i < 4; ++i) {
        uint4 u;
        u.x = cvt2(ra[i][0].x, ra[i][0].y);
        u.y = cvt2(ra[i][0].z, ra[i][0].w);
        u.z = cvt2(ra[i][1].x, ra[i][1].y);
        u.w = cvt2(ra[i][1].z, ra[i][1].w);
        *(uint4*)&At[0][(wave * 32 + i * 8 + sro) * 64 + (lane & 7) * 8] = u;
    }

    for (int kt = 0; kt < CDIM; kt += 64) {
        const int buf = (kt >> 6) & 1;
        __syncthreads();   // (a): prev compute's LDS reads + At[buf^1] writes drained
        #pragma unroll
        for (int i = 0; i < 4; ++i)
            gload_lds16(gwB + (size_t)i * 8 * CDIM + kt, &Wt[(wave * 32 + i * 8) * 64]);
        const bool pf = (kt + 64 < CDIM);
        if (pf) {
            #pragma unroll
            for (int i = 0; i < 4; ++i) {
                const float* p = gaF + (size_t)i * 8 * CDIM + kt + 64;
                ra[i][0] = *(const float4*)(p);
                ra[i][1] = *(const float4*)(p + 4);
            }
        }
        __syncthreads();   // (b): drains W gloads + A register loads together

        // compute region: convert next A tile into the other buffer (overlaps MFMA)
        if (pf) {
            ushort_t* Adst = At[buf ^ 1];
            #pragma unroll
            for (int i = 0; i < 4; ++i) {
                uint4 u;
                u.x = cvt2(ra[i][0].x, ra[i][0].y);
                u.y = cvt2(ra[i][0].z, ra[i][0].w);
                u.z = cvt2(ra[i][1].x, ra[i][1].y);
                u.w = cvt2(ra[i][1].z, ra[i][1].w);
                *(uint4*)&Adst[(wave * 32 + i * 8 + sro) * 64 + (lane & 7) * 8] = u;
            }
        }
        const ushort_t* Acur = At[buf];
        #pragma unroll
        for (int ks = 0; ks < 2; ++ks) {
            short8 af[4], bfr[4];
            #pragma unroll
            for (int mt = 0; mt < 4; ++mt) {
                const int row = wm * 64 + mt * 16 + r16;
                const int ch  = (ks * 4 + q4) ^ (row & 7);
                af[mt] = *(const short8*)&Acur[row * 64 + ch * 8];
            }
            #pragma unroll
            for (int nt = 0; nt < 4; ++nt) {
                const int row = wn * 64 + nt * 16 + r16;
                const int ch  = (ks * 4 + q4) ^ (row & 7);
                bfr[nt] = *(const short8*)&Wt[row * 64 + ch * 8];
            }
            #pragma unroll
            for (int mt = 0; mt < 4; ++mt)
                #pragma unroll
                for (int nt = 0; nt < 4; ++nt)
                    acc[mt][nt] = __builtin_amdgcn_mfma_f32_16x16x32_bf16(
                        af[mt], bfr[nt], acc[mt][nt], 0, 0, 0);
        }
    }

    // epilogue: C/D layout col=lane&15, row=(lane>>4)*4+reg -> head-major store.
    // z==0 additionally folds the adaptive-avg-pool (block's 128 rows lie in one
    // agent chunk): shfl-reduce over q4 lanes, one atomicAdd per col per wave.
    const int b = row0 >> 12;
    const int m_base = row0 & 4095;
    #pragma unroll
    for (int nt = 0; nt < 4; ++nt) {
        const int col = col0 + wn * 64 + nt * 16 + r16;
        const int h = col >> 6, d = col & 63;
        const float bb = bias[col];
        ushort_t* ob = out + ((size_t)(b * 12 + h) * 4096) * 64 + d;
        float psum = 0.f;
        #pragma unroll
        for (int mt = 0; mt < 4; ++mt) {
            const int m = m_base + wm * 64 + mt * 16 + q4 * 4;
            #pragma unroll
            for (int r = 0; r < 4; ++r) {
                ob[(size_t)(m + r) * 64] = f2bfu(acc[mt][nt][r] + bb);
                psum += acc[mt][nt][r];
            }
        }
        if (z == 0) {
            psum += __shfl_xor(psum, 16);
            psum += __shfl_xor(psum, 32);
            if (q4 == 0)
                atomicAdd(&agent[(size_t)(b * 12 + h) * 1024 + (m_base >> 8) * 64 + d],
                          psum * (1.0f / 256.0f));
        }
    }
}

// ---------- Kernel 3: stage-2 agent bias ab[h][a] (fp32) ----------
__global__ void bias_ab_k(const float* __restrict__ na, const float* __restrict__ ha,
                          const float* __restrict__ wa, float* __restrict__ ab)
{
    const int t = threadIdx.x;
    if (t >= 192) return;
    const int h = t >> 4, a = t & 15;
    const float cw[7] = {2.25f, 2.34375f, 2.28125f, 2.25f, 2.28125f, 2.34375f, 2.25f};
    float acc = 0.f;
    const float* nb = na + (h * 16 + a) * 49;
    for (int i = 0; i < 7; ++i)
        for (int j = 0; j < 7; ++j)
            acc += cw[i] * cw[j] * nb[i * 7 + j];
    acc *= (1.0f / 256.0f);
    float s = 0.f;
    for (int p = 0; p < 16; ++p)
        s += ha[(h * 16 + p) * 16 + a] + wa[(h * 16 + p) * 16 + a];
    ab[t] = acc + s * (1.0f / 16.0f);
}

// ---------- Kernel 4: stage 1 (agent -> keys/values), head-major, z-split x8 ----------
__global__ __launch_bounds__(256) void stage1(
    const ushort_t* __restrict__ k_hm, const ushort_t* __restrict__ v_hm,
    const float* __restrict__ agent, float* __restrict__ Sp, float* __restrict__ avp)
{
    const int bh = blockIdx.x, z = blockIdx.y;
    const int tid = threadIdx.x;
    __shared__ float ahs[1024];          // ah * scale, [a][d]
    __shared__ ushort_t E2[512 * 20];    // [m_local][a] bf16, row padded to 40 B

    for (int i = tid; i < 1024; i += 256)
        ahs[i] = agent[(size_t)bh * 1024 + i] * 0.125f;
    __syncthreads();

    const int m0 = z * 512;
    const ushort_t* kb = k_hm + ((size_t)bh * 4096 + m0) * 64;

    {
        const uint4* krA = (const uint4*)(kb + (size_t)tid * 64);
        const uint4* krB = (const uint4*)(kb + (size_t)(tid + 256) * 64);
        uint kuA[16], kuB[16];
        #pragma unroll
        for (int i = 0; i < 4; ++i) {
            uint4 ua = krA[i], ub = krB[i];
            kuA[i*4+0] = ua.x; kuA[i*4+1] = ua.y; kuA[i*4+2] = ua.z; kuA[i*4+3] = ua.w;
            kuB[i*4+0] = ub.x; kuB[i*4+1] = ub.y; kuB[i*4+2] = ub.z; kuB[i*4+3] = ub.w;
        }
        float dsA[16], dsB[16];
        #pragma unroll
        for (int a = 0; a < 16; ++a) { dsA[a] = 0.f; dsB[a] = 0.f; }
        #pragma unroll
        for (int c = 0; c < 16; ++c) {
            float a0, a1, a2, a3, b0, b1, b2, b3;
            bf2(kuA[2*c],   a0, a1); bf2(kuA[2*c+1], a2, a3);
            bf2(kuB[2*c],   b0, b1); bf2(kuB[2*c+1], b2, b3);
            #pragma unroll
            for (int a = 0; a < 16; ++a) {
                const floatx4 av = *(const floatx4*)&ahs[a * 64 + c * 4];
                dsA[a] += a0 * av[0] + a1 * av[1] + a2 * av[2] + a3 * av[3];
                dsB[a] += b0 * av[0] + b1 * av[1] + b2 * av[2] + b3 * av[3];
            }
        }
        uint eA[8], eB[8];
        #pragma unroll
        for (int a2 = 0; a2 < 8; ++a2) {
            eA[a2] = pack2(__expf(dsA[2*a2]), __expf(dsA[2*a2+1]));
            eB[a2] = pack2(__expf(dsB[2*a2]), __expf(dsB[2*a2+1]));
        }
        uint2* dA = (uint2*)&E2[(size_t)tid * 20];
        uint2* dB = (uint2*)&E2[(size_t)(tid + 256) * 20];
        dA[0] = make_uint2(eA[0], eA[1]); dA[1] = make_uint2(eA[2], eA[3]);
        dA[2] = make_uint2(eA[4], eA[5]); dA[3] = make_uint2(eA[6], eA[7]);
        dB[0] = make_uint2(eB[0], eB[1]); dB[1] = make_uint2(eB[2], eB[3]);
        dB[2] = make_uint2(eB[4], eB[5]); dB[3] = make_uint2(eB[6], eB[7]);
    }
    __syncthreads();

    const int d = tid & 63, g = tid >> 6;
    const ushort_t* vb = v_hm + ((size_t)bh * 4096 + m0) * 64 + d;
    float acc0 = 0, acc1 = 0, acc2 = 0, acc3 = 0;
    float ss0 = 0, ss1 = 0, ss2 = 0, ss3 = 0;
    for (int ml = 0; ml < 512; ++ml) {
        const float vv = bfu(vb[(size_t)ml * 64]);
        const uint2 ee = *(const uint2*)&E2[(size_t)ml * 20 + g * 4];
        float e0, e1, e2, e3;
        bf2(ee.x, e0, e1);
        bf2(ee.y, e2, e3);
        acc0 += e0 * vv; ss0 += e0;
        acc1 += e1 * vv; ss1 += e1;
        acc2 += e2 * vv; ss2 += e2;
        acc3 += e3 * vv; ss3 += e3;
    }
    float* avz = avp + (size_t)(z * 96 + bh) * 1024;
    avz[(g * 4 + 0) * 64 + d] = acc0;
    avz[(g * 4 + 1) * 64 + d] = acc1;
    avz[(g * 4 + 2) * 64 + d] = acc2;
    avz[(g * 4 + 3) * 64 + d] = acc3;
    if (d == 0) {
        float* Sz = Sp + (z * 96 + bh) * 16;
        Sz[g * 4 + 0] = ss0;
        Sz[g * 4 + 1] = ss1;
        Sz[g * 4 + 2] = ss2;
        Sz[g * 4 + 3] = ss3;
    }
}

// ---------- Kernel 5: stage 2 (queries -> agents) + fp32 output ----------
__global__ __launch_bounds__(256) void stage2(
    const ushort_t* __restrict__ q_hm, const float* __restrict__ avp,
    const float* __restrict__ Sp, const float* __restrict__ agent,
    const float* __restrict__ ab, float* __restrict__ out)
{
    const int nb = blockIdx.x, bh = blockIdx.y;
    const int b = bh / 12, h = bh % 12;
    const int tid = threadIdx.x;
    __shared__ float ahs[1024];
    __shared__ float avn[1024];
    __shared__ float abl[16];

    for (int i = tid; i < 1024; i += 256) {
        const int a = i >> 6;
        ahs[i] = agent[(size_t)bh * 1024 + i] * 0.125f;
        float num = 0.f, den = 0.f;
        #pragma unroll
        for (int zz = 0; zz < 8; ++zz) {
            num += avp[(size_t)(zz * 96 + bh) * 1024 + i];
            den += Sp[(zz * 96 + bh) * 16 + a];
        }
        avn[i] = num / den;
    }
    if (tid < 16) abl[tid] = ab[h * 16 + tid];
    __syncthreads();

    const int n0 = nb * 512;
    const uint4* qrA = (const uint4*)(q_hm + ((size_t)bh * 4096 + n0 + tid) * 64);
    const uint4* qrB = (const uint4*)(q_hm + ((size_t)bh * 4096 + n0 + tid + 256) * 64);
    uint quA[16], quB[16];
    #pragma unroll
    for (int i = 0; i < 4; ++i) {
        uint4 ua = qrA[i], ub = qrB[i];
        quA[i*4+0] = ua.x; quA[i*4+1] = ua.y; quA[i*4+2] = ua.z; quA[i*4+3] = ua.w;
        quB[i*4+0] = ub.x; quB[i*4+1] = ub.y; quB[i*4+2] = ub.z; quB[i*4+3] = ub.w;
    }
    float dsA[16], dsB[16];
    #pragma unroll
    for (int a = 0; a < 16; ++a) { float t = abl[a]; dsA[a] = t; dsB[a] = t; }
    #pragma unroll
    for (int c = 0; c < 16; ++c) {
        float a0, a1, a2, a3, b0, b1, b2, b3;
        bf2(quA[2*c],   a0, a1); bf2(quA[2*c+1], a2, a3);
        bf2(quB[2*c],   b0, b1); bf2(quB[2*c+1], b2, b3);
        #pragma unroll
        for (int a = 0; a < 16; ++a) {
            const floatx4 av = *(const floatx4*)&ahs[a * 64 + c * 4];
            dsA[a] += a0 * av[0] + a1 * av[1] + a2 * av[2] + a3 * av[3];
            dsB[a] += b0 * av[0] + b1 * av[1] + b2 * av[2] + b3 * av[3];
        }
    }
    float psA = 0.f, psB = 0.f;
    #pragma unroll
    for (int a = 0; a < 16; ++a) {
        dsA[a] = __expf(dsA[a]); psA += dsA[a];
        dsB[a] = __expf(dsB[a]); psB += dsB[a];
    }
    const float rA = 1.0f / psA, rB = 1.0f / psB;
    #pragma unroll
    for (int a = 0; a < 16; ++a) { dsA[a] *= rA; dsB[a] *= rB; }

    float* oA = out + ((size_t)b * 4096 + n0 + tid) * CDIM + h * 64;
    float* oB = oA + (size_t)256 * CDIM;
    #pragma unroll
    for (int dc = 0; dc < 16; ++dc) {
        floatx4 sA = {0.f, 0.f, 0.f, 0.f}, sB = {0.f, 0.f, 0.f, 0.f};
        #pragma unroll
        for (int a = 0; a < 16; ++a) {
            const floatx4 av = *(const floatx4*)&avn[a * 64 + dc * 4];
            sA += dsA[a] * av;
            sB += dsB[a] * av;
        }
        *(floatx4*)(oA + dc * 4) = sA;
        *(floatx4*)(oB + dc * 4) = sB;
    }
}

// ---------- launcher ----------
extern "C" void kernel_launch(void* const* d_in, const int* in_sizes, int n_in,
                              void* d_out, int out_size, void* d_ws, size_t ws_size,
                              hipStream_t stream) {
    (void)in_sizes; (void)n_in; (void)out_size; (void)ws_size;
    const float* s1 = (const float*)d_in[0];
    const float* s2 = (const float*)d_in[1];
    const float* Wq = (const float*)d_in[2];
    const float* bq = (const float*)d_in[3];
    const float* Wk = (const float*)d_in[4];
    const float* bk = (const float*)d_in[5];
    const float* Wv = (const float*)d_in[6];
    const float* bv = (const float*)d_in[7];
    const float* na = (const float*)d_in[9];
    const float* ha = (const float*)d_in[12];
    const float* wa = (const float*)d_in[13];
    float* out = (float*)d_out;

    char* ws = (char*)d_ws;
    ushort_t* q_hm = (ushort_t*)(ws);                 // 50,331,648 B  [96][4096][64]
    ushort_t* k_hm = (ushort_t*)(ws + 50331648);      // 50,331,648 B
    ushort_t* v_hm = (ushort_t*)(ws + 100663296);     // 50,331,648 B
    float* agent   = (float*)(ws + 150994944);        //    393,216 B  [96][16][64]
    float* Sp      = (float*)(ws + 151388160);        //     49,152 B  [8][96][16]
    float* avp     = (float*)(ws + 151437312);        //  3,145,728 B  [8][96][16][64]
    float* ab      = (float*)(ws + 154583040);        //        768 B
    ushort_t* wb   = (ushort_t*)(ws + 154583808);     //  3,538,944 B  [3][768][768]

    cvt_w      <<<dim3(288, 3),    256, 0, stream>>>(Wq, Wk, Wv, wb);
    init_agent <<<dim3(96),        256, 0, stream>>>(bq, agent);
    gemm_qkv   <<<dim3(256, 6, 3), 256, 0, stream>>>(s1, s2, wb, bq, bk, bv,
                                                     q_hm, k_hm, v_hm, agent);
    bias_ab_k  <<<1, 256, 0, stream>>>(na, ha, wa, ab);
    stage1     <<<dim3(96, 8),     256, 0, stream>>>(k_hm, v_hm, agent, Sp, avp);
    stage2     <<<dim3(8, 96),     256, 0, stream>>>(q_hm, avp, Sp, agent, ab, out);
}

// Round 5
// 304.437 us; speedup vs baseline: 1.1510x; 1.0849x over previous
//
#include <hip/hip_runtime.h>
#include <cstdint>
#include <cstddef>

typedef unsigned short ushort_t;
typedef unsigned int uint;

typedef __attribute__((ext_vector_type(8))) short short8;   // 8 x bf16 (4 VGPRs)
typedef __attribute__((ext_vector_type(4))) float floatx4;  // 4 x f32

#define CDIM 768

// ---------- bf16 helpers (raw ushort representation) ----------
__device__ __forceinline__ float bfu(ushort_t u) {
    return __uint_as_float(((uint)u) << 16);
}
__device__ __forceinline__ void bf2(uint u, float& lo, float& hi) {
    lo = __uint_as_float(u << 16);
    hi = __uint_as_float(u & 0xffff0000u);
}
__device__ __forceinline__ ushort_t f2bfu(float f) {
    uint u = __float_as_uint(f);
    u += 0x7fffu + ((u >> 16) & 1u);   // round-to-nearest-even
    return (ushort_t)(u >> 16);
}
__device__ __forceinline__ uint pack2(float a, float b) {     // RNE pack
    return (uint)f2bfu(a) | ((uint)f2bfu(b) << 16);
}
// packed RNE f32x2 -> bf16x2 (low word = first operand), 1 VALU inst
__device__ __forceinline__ uint cvt2(float lo, float hi) {
    uint r;
    asm("v_cvt_pk_bf16_f32 %0, %1, %2" : "=v"(r) : "v"(lo), "v"(hi));
    return r;
}
__device__ __forceinline__ short8 mk8(uint a, uint b, uint c, uint d) {
    union { uint4 u; short8 s; } x;
    x.u = (uint4){a, b, c, d};
    return x.s;
}
__device__ __forceinline__ void gload_lds16(const void* g, void* l) {
    __builtin_amdgcn_global_load_lds(
        (__attribute__((address_space(1))) void*)(uintptr_t)g,
        (__attribute__((address_space(3))) void*)l, 16, 0, 0);
}

// ---------- Kernel 0a: convert Wq/Wk/Wv (fp32) -> bf16, RNE ----------
__global__ __launch_bounds__(256) void cvt_w(
    const float* __restrict__ Wq, const float* __restrict__ Wk,
    const float* __restrict__ Wv, ushort_t* __restrict__ wb)
{
    const int m = blockIdx.y;
    const float* src = (m == 0) ? Wq : (m == 1 ? Wk : Wv);
    ushort_t* dst = wb + (size_t)m * 589824;
    const int i = (blockIdx.x * 256 + threadIdx.x) * 8;
    const float4 f0 = *(const float4*)(src + i);
    const float4 f1 = *(const float4*)(src + i + 4);
    uint4 u;
    u.x = pack2(f0.x, f0.y);
    u.y = pack2(f0.z, f0.w);
    u.z = pack2(f1.x, f1.y);
    u.w = pack2(f1.z, f1.w);
    *(uint4*)(dst + i) = u;
}

// ---------- Kernel 0b: init agent accumulator with the q-bias ----------
__global__ __launch_bounds__(256) void init_agent(const float* __restrict__ bq,
                                                  float* __restrict__ agent)
{
    const int bh = blockIdx.x;          // 96
    const int h = bh % 12;
    for (int i = threadIdx.x; i < 1024; i += 256)
        agent[(size_t)bh * 1024 + i] = bq[h * 64 + (i & 63)];
}

// ---------- Kernel 1: fused QKV GEMM (round-2 proven version) ----------
// A read as fp32 (s1/s2), converted in-register (v_cvt_pk_bf16_f32) between the
// barriers, ds_written into the XOR-swizzled LDS layout. Next-tile A loads are
// issued after the second barrier so they fly during compute.
__global__ __launch_bounds__(256, 2) void gemm_qkv(
    const float* __restrict__ s1, const float* __restrict__ s2,
    const ushort_t* __restrict__ wb,
    const float* __restrict__ bq, const float* __restrict__ bk, const float* __restrict__ bv,
    ushort_t* __restrict__ qo, ushort_t* __restrict__ ko, ushort_t* __restrict__ vo,
    float* __restrict__ agent)
{
    const int z = blockIdx.z;
    const float* A        = (z == 0) ? s1 : s2;
    const ushort_t* W     = wb + (size_t)z * 589824;
    const float* bias     = (z == 0) ? bq : (z == 1 ? bk : bv);
    ushort_t* out         = (z == 0) ? qo : (z == 1 ? ko : vo);

    __shared__ ushort_t At[128 * 64];   // 16 KB
    __shared__ ushort_t Wt[128 * 64];   // 16 KB

    const int tid  = threadIdx.x;
    const int wave = tid >> 6;
    const int lane = tid & 63;
    const int wm = wave >> 1, wn = wave & 1;

    // XCD-aware swizzle: 1536 blocks/plane, 8 XCDs, 192 blocks/chunk (bijective).
    const int id   = blockIdx.x + (blockIdx.y << 8);   // gridDim.x = 256
    const int id2  = (id & 7) * 192 + (id >> 3);
    const int row0 = (id2 / 6) * 128;   // token rows (b*4096+m)
    const int col0 = (id2 % 6) * 128;   // output channels

    // staging geometry: lane j covers row_off = j>>3, source chunk = (j&7) ^ (j>>3)
    const int sro = lane >> 3;
    const int sch = ((lane & 7) ^ sro) * 8;
    const float*    gaF = A + (size_t)(row0 + wave * 32 + sro) * CDIM + sch;
    const ushort_t* gwB = W + (size_t)(col0 + wave * 32 + sro) * CDIM + sch;

    floatx4 acc[4][4];
    #pragma unroll
    for (int i = 0; i < 4; ++i)
        #pragma unroll
        for (int j = 0; j < 4; ++j)
            acc[i][j] = (floatx4){0.f, 0.f, 0.f, 0.f};

    const int q4 = lane >> 4, r16 = lane & 15;

    // prefetch A (fp32) for kt = 0
    float4 ra[4][2];
    #pragma unroll
    for (int i = 0; i < 4; ++i) {
        const float* p = gaF + (size_t)i * 8 * CDIM;
        ra[i][0] = *(const float4*)(p);
        ra[i][1] = *(const float4*)(p + 4);
    }

    for (int kt = 0; kt < CDIM; kt += 64) {
        __syncthreads();
        #pragma unroll
        for (int i = 0; i < 4; ++i)
            gload_lds16(gwB + (size_t)i * 8 * CDIM + kt, &Wt[(wave * 32 + i * 8) * 64]);
        #pragma unroll
        for (int i = 0; i < 4; ++i) {
            uint4 u;
            u.x = cvt2(ra[i][0].x, ra[i][0].y);
            u.y = cvt2(ra[i][0].z, ra[i][0].w);
            u.z = cvt2(ra[i][1].x, ra[i][1].y);
            u.w = cvt2(ra[i][1].z, ra[i][1].w);
            // dest chunk = lane&7; holds source chunk (lane&7)^sro  ==  c^(row&7)
            *(uint4*)&At[(wave * 32 + i * 8 + sro) * 64 + (lane & 7) * 8] = u;
        }
        __syncthreads();
        // issue next tile's A loads AFTER the barrier -> they fly during compute
        if (kt + 64 < CDIM) {
            #pragma unroll
            for (int i = 0; i < 4; ++i) {
                const float* p = gaF + (size_t)i * 8 * CDIM + kt + 64;
                ra[i][0] = *(const float4*)(p);
                ra[i][1] = *(const float4*)(p + 4);
            }
        }
        #pragma unroll
        for (int ks = 0; ks < 2; ++ks) {
            short8 af[4], bfr[4];
            #pragma unroll
            for (int mt = 0; mt < 4; ++mt) {
                const int row = wm * 64 + mt * 16 + r16;
                const int ch  = (ks * 4 + q4) ^ (row & 7);
                af[mt] = *(const short8*)&At[row * 64 + ch * 8];
            }
            #pragma unroll
            for (int nt = 0; nt < 4; ++nt) {
                const int row = wn * 64 + nt * 16 + r16;
                const int ch  = (ks * 4 + q4) ^ (row & 7);
                bfr[nt] = *(const short8*)&Wt[row * 64 + ch * 8];
            }
            #pragma unroll
            for (int mt = 0; mt < 4; ++mt)
                #pragma unroll
                for (int nt = 0; nt < 4; ++nt)
                    acc[mt][nt] = __builtin_amdgcn_mfma_f32_16x16x32_bf16(
                        af[mt], bfr[nt], acc[mt][nt], 0, 0, 0);
        }
    }

    // epilogue: C/D layout col=lane&15, row=(lane>>4)*4+reg -> head-major store.
    // z==0 additionally folds the adaptive-avg-pool.
    const int b = row0 >> 12;
    const int m_base = row0 & 4095;
    #pragma unroll
    for (int nt = 0; nt < 4; ++nt) {
        const int col = col0 + wn * 64 + nt * 16 + r16;
        const int h = col >> 6, d = col & 63;
        const float bb = bias[col];
        ushort_t* ob = out + ((size_t)(b * 12 + h) * 4096) * 64 + d;
        float psum = 0.f;
        #pragma unroll
        for (int mt = 0; mt < 4; ++mt) {
            const int m = m_base + wm * 64 + mt * 16 + q4 * 4;
            #pragma unroll
            for (int r = 0; r < 4; ++r) {
                ob[(size_t)(m + r) * 64] = f2bfu(acc[mt][nt][r] + bb);
                psum += acc[mt][nt][r];
            }
        }
        if (z == 0) {
            psum += __shfl_xor(psum, 16);
            psum += __shfl_xor(psum, 32);
            if (q4 == 0)
                atomicAdd(&agent[(size_t)(b * 12 + h) * 1024 + (m_base >> 8) * 64 + d],
                          psum * (1.0f / 256.0f));
        }
    }
}

// ---------- Kernel 3: stage-2 agent bias ab[h][a] (fp32) ----------
__global__ void bias_ab_k(const float* __restrict__ na, const float* __restrict__ ha,
                          const float* __restrict__ wa, float* __restrict__ ab)
{
    const int t = threadIdx.x;
    if (t >= 192) return;
    const int h = t >> 4, a = t & 15;
    const float cw[7] = {2.25f, 2.34375f, 2.28125f, 2.25f, 2.28125f, 2.34375f, 2.25f};
    float acc = 0.f;
    const float* nb = na + (h * 16 + a) * 49;
    for (int i = 0; i < 7; ++i)
        for (int j = 0; j < 7; ++j)
            acc += cw[i] * cw[j] * nb[i * 7 + j];
    acc *= (1.0f / 256.0f);
    float s = 0.f;
    for (int p = 0; p < 16; ++p)
        s += ha[(h * 16 + p) * 16 + a] + wa[(h * 16 + p) * 16 + a];
    ab[t] = acc + s * (1.0f / 16.0f);
}

// ---------- Kernel 4: stage 1 (agent -> keys/values), head-major, z-split x8 ----------
__global__ __launch_bounds__(256) void stage1(
    const ushort_t* __restrict__ k_hm, const ushort_t* __restrict__ v_hm,
    const float* __restrict__ agent, float* __restrict__ Sp, float* __restrict__ avp)
{
    const int bh = blockIdx.x, z = blockIdx.y;
    const int tid = threadIdx.x;
    __shared__ float ahs[1024];          // ah * scale, [a][d]
    __shared__ ushort_t E2[512 * 20];    // [m_local][a] bf16, row padded to 40 B

    for (int i = tid; i < 1024; i += 256)
        ahs[i] = agent[(size_t)bh * 1024 + i] * 0.125f;
    __syncthreads();

    const int m0 = z * 512;
    const ushort_t* kb = k_hm + ((size_t)bh * 4096 + m0) * 64;

    {
        const uint4* krA = (const uint4*)(kb + (size_t)tid * 64);
        const uint4* krB = (const uint4*)(kb + (size_t)(tid + 256) * 64);
        uint kuA[16], kuB[16];
        #pragma unroll
        for (int i = 0; i < 4; ++i) {
            uint4 ua = krA[i], ub = krB[i];
            kuA[i*4+0] = ua.x; kuA[i*4+1] = ua.y; kuA[i*4+2] = ua.z; kuA[i*4+3] = ua.w;
            kuB[i*4+0] = ub.x; kuB[i*4+1] = ub.y; kuB[i*4+2] = ub.z; kuB[i*4+3] = ub.w;
        }
        float dsA[16], dsB[16];
        #pragma unroll
        for (int a = 0; a < 16; ++a) { dsA[a] = 0.f; dsB[a] = 0.f; }
        #pragma unroll
        for (int c = 0; c < 16; ++c) {
            float a0, a1, a2, a3, b0, b1, b2, b3;
            bf2(kuA[2*c],   a0, a1); bf2(kuA[2*c+1], a2, a3);
            bf2(kuB[2*c],   b0, b1); bf2(kuB[2*c+1], b2, b3);
            #pragma unroll
            for (int a = 0; a < 16; ++a) {
                const floatx4 av = *(const floatx4*)&ahs[a * 64 + c * 4];
                dsA[a] += a0 * av[0] + a1 * av[1] + a2 * av[2] + a3 * av[3];
                dsB[a] += b0 * av[0] + b1 * av[1] + b2 * av[2] + b3 * av[3];
            }
        }
        uint eA[8], eB[8];
        #pragma unroll
        for (int a2 = 0; a2 < 8; ++a2) {
            eA[a2] = pack2(__expf(dsA[2*a2]), __expf(dsA[2*a2+1]));
            eB[a2] = pack2(__expf(dsB[2*a2]), __expf(dsB[2*a2+1]));
        }
        uint2* dA = (uint2*)&E2[(size_t)tid * 20];
        uint2* dB = (uint2*)&E2[(size_t)(tid + 256) * 20];
        dA[0] = make_uint2(eA[0], eA[1]); dA[1] = make_uint2(eA[2], eA[3]);
        dA[2] = make_uint2(eA[4], eA[5]); dA[3] = make_uint2(eA[6], eA[7]);
        dB[0] = make_uint2(eB[0], eB[1]); dB[1] = make_uint2(eB[2], eB[3]);
        dB[2] = make_uint2(eB[4], eB[5]); dB[3] = make_uint2(eB[6], eB[7]);
    }
    __syncthreads();

    const int d = tid & 63, g = tid >> 6;
    const ushort_t* vb = v_hm + ((size_t)bh * 4096 + m0) * 64 + d;
    float acc0 = 0, acc1 = 0, acc2 = 0, acc3 = 0;
    float ss0 = 0, ss1 = 0, ss2 = 0, ss3 = 0;
    for (int ml = 0; ml < 512; ++ml) {
        const float vv = bfu(vb[(size_t)ml * 64]);
        const uint2 ee = *(const uint2*)&E2[(size_t)ml * 20 + g * 4];
        float e0, e1, e2, e3;
        bf2(ee.x, e0, e1);
        bf2(ee.y, e2, e3);
        acc0 += e0 * vv; ss0 += e0;
        acc1 += e1 * vv; ss1 += e1;
        acc2 += e2 * vv; ss2 += e2;
        acc3 += e3 * vv; ss3 += e3;
    }
    float* avz = avp + (size_t)(z * 96 + bh) * 1024;
    avz[(g * 4 + 0) * 64 + d] = acc0;
    avz[(g * 4 + 1) * 64 + d] = acc1;
    avz[(g * 4 + 2) * 64 + d] = acc2;
    avz[(g * 4 + 3) * 64 + d] = acc3;
    if (d == 0) {
        float* Sz = Sp + (z * 96 + bh) * 16;
        Sz[g * 4 + 0] = ss0;
        Sz[g * 4 + 1] = ss1;
        Sz[g * 4 + 2] = ss2;
        Sz[g * 4 + 3] = ss3;
    }
}

// ---------- Kernel 5: stage 2 (queries -> agents) via MFMA ----------
// Swapped-operand scheme (no transposes):
//  S^T[a][tok] = mfma(A=ah, B=Q) per 16-token tile; C/D: col=lane&15=tok,
//  row=4*(lane>>4)+r=agent. Softmax over agents = 3 in-lane adds + 2 shfl_xor.
//  PV: out^T[d][tok] = mfma(A=av^T, B=P^T) with K=32 zero-padded; the P^T
//  B-fragment is built from the S^T C/D registers by a 2-source-lane regroup
//  (4 shfls). Residual (value+err) fragments for ah, av, P keep fp32-level
//  accuracy. Output C/D = out^T tile -> direct coalesced float4 stores.
__global__ __launch_bounds__(256) void stage2(
    const ushort_t* __restrict__ q_hm, const float* __restrict__ avp,
    const float* __restrict__ Sp, const float* __restrict__ agent,
    const float* __restrict__ ab, float* __restrict__ out)
{
    const int nb = blockIdx.x;           // 16
    const int bh = blockIdx.y;           // 96
    const int b = bh / 12, h = bh % 12;
    const int tid = threadIdx.x;
    const int g = (tid >> 4) & 3;        // lane>>4 (quad group)
    const int t = tid & 15;              // lane&15
    const int w = tid >> 6;              // wave
    __shared__ float avn[1024];          // normalized agent_v, [a][d] fp32

    // avn = (sum_z avp) / (sum_z Sp)
    {
        const int i4 = tid * 4;
        const int a = i4 >> 6;
        floatx4 num = {0.f, 0.f, 0.f, 0.f};
        float den = 0.f;
        #pragma unroll
        for (int zz = 0; zz < 8; ++zz) {
            num += *(const floatx4*)&avp[(size_t)(zz * 96 + bh) * 1024 + i4];
            den += Sp[(zz * 96 + bh) * 16 + a];
        }
        const float r = 1.0f / den;
        *(floatx4*)&avn[i4] = num * r;
    }
    __syncthreads();

    // ah A-fragments (value + residual): lane holds ah[t][k0*32 + g*8 + j]*scale
    short8 ahA[2], ahE[2];
    #pragma unroll
    for (int k0 = 0; k0 < 2; ++k0) {
        const float* p = agent + (size_t)bh * 1024 + t * 64 + k0 * 32 + g * 8;
        const float4 f0 = *(const float4*)p;
        const float4 f1 = *(const float4*)(p + 4);
        const float v[8] = {f0.x, f0.y, f0.z, f0.w, f1.x, f1.y, f1.z, f1.w};
        uint u[4], e[4];
        #pragma unroll
        for (int j = 0; j < 4; ++j) {
            const float a0 = v[2*j] * 0.125f, a1 = v[2*j+1] * 0.125f;
            u[j] = cvt2(a0, a1);
            float b0, b1; bf2(u[j], b0, b1);
            e[j] = cvt2(a0 - b0, a1 - b1);
        }
        ahA[k0] = mk8(u[0], u[1], u[2], u[3]);
        ahE[k0] = mk8(e[0], e[1], e[2], e[3]);
    }

    // av^T A-fragments (value + residual): lane holds avn[8g+j][dt*16 + t]; g>=2 zero
    short8 avf[4], ave[4];
    #pragma unroll
    for (int dt = 0; dt < 4; ++dt) {
        uint u[4] = {0, 0, 0, 0}, e[4] = {0, 0, 0, 0};
        if (g < 2) {
            #pragma unroll
            for (int j = 0; j < 4; ++j) {
                const float a0 = avn[(8*g + 2*j)     * 64 + dt * 16 + t];
                const float a1 = avn[(8*g + 2*j + 1) * 64 + dt * 16 + t];
                u[j] = cvt2(a0, a1);
                float b0, b1; bf2(u[j], b0, b1);
                e[j] = cvt2(a0 - b0, a1 - b1);
            }
        }
        avf[dt] = mk8(u[0], u[1], u[2], u[3]);
        ave[dt] = mk8(e[0], e[1], e[2], e[3]);
    }

    float abv[4];
    #pragma unroll
    for (int r = 0; r < 4; ++r) abv[r] = ab[h * 16 + 4 * g + r];

    const int src0 = (t + 32 * g) & 63;
    const int src1 = (src0 + 16) & 63;
    const int n0 = nb * 256 + w * 64;
    const ushort_t* qb = q_hm + ((size_t)bh * 4096 + n0) * 64;
    float* ob = out + ((size_t)b * 4096 + n0) * CDIM + h * 64;

    #pragma unroll
    for (int ti = 0; ti < 4; ++ti) {
        // Q B-fragments: lane holds Q[ti*16+t][k0*32 + g*8 + j]
        const ushort_t* qp = qb + (size_t)(ti * 16 + t) * 64 + g * 8;
        const short8 qB0 = *(const short8*)(qp);
        const short8 qB1 = *(const short8*)(qp + 32);

        floatx4 sc = {0.f, 0.f, 0.f, 0.f};
        sc = __builtin_amdgcn_mfma_f32_16x16x32_bf16(ahA[0], qB0, sc, 0, 0, 0);
        sc = __builtin_amdgcn_mfma_f32_16x16x32_bf16(ahA[1], qB1, sc, 0, 0, 0);
        sc = __builtin_amdgcn_mfma_f32_16x16x32_bf16(ahE[0], qB0, sc, 0, 0, 0);
        sc = __builtin_amdgcn_mfma_f32_16x16x32_bf16(ahE[1], qB1, sc, 0, 0, 0);

        // softmax over agents (rows): in-lane + cross-group
        const float e0 = __expf(sc[0] + abv[0]);
        const float e1 = __expf(sc[1] + abv[1]);
        const float e2 = __expf(sc[2] + abv[2]);
        const float e3 = __expf(sc[3] + abv[3]);
        float s = e0 + e1 + e2 + e3;
        s += __shfl_xor(s, 16);
        s += __shfl_xor(s, 32);
        const float rs = 1.0f / s;
        const float p0 = e0 * rs, p1 = e1 * rs, p2 = e2 * rs, p3 = e3 * rs;

        // pack own P (agents 4g..4g+3, token t) + residual
        const uint P0 = cvt2(p0, p1), P1 = cvt2(p2, p3);
        float q0, q1, q2, q3;
        bf2(P0, q0, q1); bf2(P1, q2, q3);
        const uint E0 = cvt2(p0 - q0, p1 - q1), E1 = cvt2(p2 - q2, p3 - q3);

        // regroup into K=32-padded B-fragment: k=8g+j -> agents from groups 2g, 2g+1
        uint w0 = __shfl(P0, src0), w1 = __shfl(P1, src0);
        uint w2 = __shfl(P0, src1), w3 = __shfl(P1, src1);
        uint x0 = __shfl(E0, src0), x1 = __shfl(E1, src0);
        uint x2 = __shfl(E0, src1), x3 = __shfl(E1, src1);
        if (g >= 2) { w0 = w1 = w2 = w3 = 0; x0 = x1 = x2 = x3 = 0; }
        const short8 pf = mk8(w0, w1, w2, w3);
        const short8 pe = mk8(x0, x1, x2, x3);

        // PV: out^T[dt*16 + 4g + r][t], residual-corrected
        float* op = ob + (size_t)(ti * 16 + t) * CDIM + 4 * g;
        #pragma unroll
        for (int dt = 0; dt < 4; ++dt) {
            floatx4 od = {0.f, 0.f, 0.f, 0.f};
            od = __builtin_amdgcn_mfma_f32_16x16x32_bf16(avf[dt], pf, od, 0, 0, 0);
            od = __builtin_amdgcn_mfma_f32_16x16x32_bf16(avf[dt], pe, od, 0, 0, 0);
            od = __builtin_amdgcn_mfma_f32_16x16x32_bf16(ave[dt], pf, od, 0, 0, 0);
            *(floatx4*)(op + dt * 16) = od;
        }
    }
}

// ---------- launcher ----------
extern "C" void kernel_launch(void* const* d_in, const int* in_sizes, int n_in,
                              void* d_out, int out_size, void* d_ws, size_t ws_size,
                              hipStream_t stream) {
    (void)in_sizes; (void)n_in; (void)out_size; (void)ws_size;
    const float* s1 = (const float*)d_in[0];
    const float* s2 = (const float*)d_in[1];
    const float* Wq = (const float*)d_in[2];
    const float* bq = (const float*)d_in[3];
    const float* Wk = (const float*)d_in[4];
    const float* bk = (const float*)d_in[5];
    const float* Wv = (const float*)d_in[6];
    const float* bv = (const float*)d_in[7];
    const float* na = (const float*)d_in[9];
    const float* ha = (const float*)d_in[12];
    const float* wa = (const float*)d_in[13];
    float* out = (float*)d_out;

    char* ws = (char*)d_ws;
    ushort_t* q_hm = (ushort_t*)(ws);                 // 50,331,648 B  [96][4096][64]
    ushort_t* k_hm = (ushort_t*)(ws + 50331648);      // 50,331,648 B
    ushort_t* v_hm = (ushort_t*)(ws + 100663296);     // 50,331,648 B
    float* agent   = (float*)(ws + 150994944);        //    393,216 B  [96][16][64]
    float* Sp      = (float*)(ws + 151388160);        //     49,152 B  [8][96][16]
    float* avp     = (float*)(ws + 151437312);        //  3,145,728 B  [8][96][16][64]
    float* ab      = (float*)(ws + 154583040);        //        768 B
    ushort_t* wb   = (ushort_t*)(ws + 154583808);     //  3,538,944 B  [3][768][768]

    cvt_w      <<<dim3(288, 3),    256, 0, stream>>>(Wq, Wk, Wv, wb);
    init_agent <<<dim3(96),        256, 0, stream>>>(bq, agent);
    gemm_qkv   <<<dim3(256, 6, 3), 256, 0, stream>>>(s1, s2, wb, bq, bk, bv,
                                                     q_hm, k_hm, v_hm, agent);
    bias_ab_k  <<<1, 256, 0, stream>>>(na, ha, wa, ab);
    stage1     <<<dim3(96, 8),     256, 0, stream>>>(k_hm, v_hm, agent, Sp, avp);
    stage2     <<<dim3(16, 96),    256, 0, stream>>>(q_hm, avp, Sp, agent, ab, out);
}